// Round 7
// baseline (139.959 us; speedup 1.0000x reference)
//
#include <hip/hip_runtime.h>
#include <hip/hip_bf16.h>
#include <math.h>

#define B_     8192
#define LATENT 32
#define CIN    128
#define HID    256
#define ACTD   16
#define NE     8
#define GH     128
#define IN0    160   // LATENT + CIN
#define INTER  288   // HID + LATENT

typedef __attribute__((ext_vector_type(8))) short short8;
typedef __attribute__((ext_vector_type(4))) short short4v;
typedef __attribute__((ext_vector_type(4))) float f32x4;
typedef __attribute__((ext_vector_type(4))) int   i32x4;

__device__ __forceinline__ float elu1(float x) { return x > 0.0f ? x : expm1f(x); }

__device__ __forceinline__ unsigned short bfh(float v) {
    __hip_bfloat16 b = __float2bfloat16(v);
    return *reinterpret_cast<unsigned short*>(&b);
}
__device__ __forceinline__ float bf2f(unsigned short u) {
    __hip_bfloat16 b;
    *reinterpret_cast<unsigned short*>(&b) = u;
    return __bfloat162float(b);
}
__device__ __forceinline__ void gload16(const unsigned short* g, const char* lds) {
    __builtin_amdgcn_global_load_lds((const __attribute__((address_space(1))) void*)g,
                                     (__attribute__((address_space(3))) void*)lds, 16, 0, 0);
}
__device__ __forceinline__ short8 as_s8(i32x4 v) {
    union U { i32x4 a; short8 b; } u; u.a = v; return u.b;
}

// ---------- prep (gather form): coalesced short8 writes, strided reads ----------
__global__ __launch_bounds__(256) void k_prep_g(
    const float* __restrict__ w0, const float* __restrict__ w1, const float* __restrict__ w2,
    const float* __restrict__ g0w, const float* __restrict__ g1w,
    unsigned short* __restrict__ T0h, unsigned short* __restrict__ T0l,
    unsigned short* __restrict__ T1h, unsigned short* __restrict__ T1l,
    unsigned short* __restrict__ T2h, unsigned short* __restrict__ T2l,
    unsigned short* __restrict__ G0h, unsigned short* __restrict__ G0l,
    unsigned short* __restrict__ G1h, unsigned short* __restrict__ G1l)
{
    int g = blockIdx.x * 256 + threadIdx.x;
    const float* src; int stride; size_t dst; unsigned short *H, *L;
    if (g < 40960) {                       // T0: [8][160][256] -> [8*256][160]
        int e = g / 5120, r = g % 5120, o = r / 20, i0 = (r % 20) * 8;
        src = w0 + ((size_t)e * 160 + i0) * 256 + o; stride = 256;
        dst = ((size_t)e * 256 + o) * 160 + i0; H = T0h; L = T0l;
    } else if (g < 114688) {               // T1: [8][288][256] -> [8*256][288]
        int t = g - 40960;
        int e = t / 9216, r = t % 9216, o = r / 36, i0 = (r % 36) * 8;
        src = w1 + ((size_t)e * 288 + i0) * 256 + o; stride = 256;
        dst = ((size_t)e * 256 + o) * 288 + i0; H = T1h; L = T1l;
    } else if (g < 119296) {               // T2: [8][288][16] -> [8*16][288]
        int t = g - 114688;
        int e = t / 576, r = t % 576, o = r / 36, i0 = (r % 36) * 8;
        src = w2 + ((size_t)e * 288 + i0) * 16 + o; stride = 16;
        dst = ((size_t)e * 16 + o) * 288 + i0; H = T2h; L = T2l;
    } else if (g < 121856) {               // G0: [160][128] -> [128][160]
        int t = g - 119296;
        int o = t / 20, i0 = (t % 20) * 8;
        src = g0w + (size_t)i0 * 128 + o; stride = 128;
        dst = (size_t)o * 160 + i0; H = G0h; L = G0l;
    } else if (g < 123904) {               // G1: [128][128] -> [128][128]
        int t = g - 121856;
        int o = t / 16, i0 = (t % 16) * 8;
        src = g1w + (size_t)i0 * 128 + o; stride = 128;
        dst = (size_t)o * 128 + i0; H = G1h; L = G1l;
    } else return;
    unsigned short hh[8], ll[8];
    #pragma unroll
    for (int j = 0; j < 8; ++j) {
        float v = src[(size_t)j * stride];
        hh[j] = bfh(v);
        ll[j] = bfh(v - bf2f(hh[j]));
    }
    *(short8*)&H[dst] = *(const short8*)hh;
    *(short8*)&L[dst] = *(const short8*)ll;
}

// ---------- LayerNorm + concat, split to hi/lo; also seed z into X1/X2 ----------
__global__ __launch_bounds__(256) void k_ln_concat2(
    const float* __restrict__ z, const float* __restrict__ c,
    const float* __restrict__ g, const float* __restrict__ bt,
    unsigned short* __restrict__ X0h, unsigned short* __restrict__ X0l,
    unsigned short* __restrict__ X1h, unsigned short* __restrict__ X1l,
    unsigned short* __restrict__ X2h, unsigned short* __restrict__ X2l)
{
    int gid = blockIdx.x * 256 + threadIdx.x;
    int row = gid >> 6;
    int l = threadIdx.x & 63;
    if (row >= B_) return;
    const float* cr = c + (size_t)row * CIN;
    float v0 = cr[l], v1 = cr[l + 64];
    float s = v0 + v1;
    #pragma unroll
    for (int o = 32; o; o >>= 1) s += __shfl_xor(s, o);
    float mean = s * (1.0f / 128.0f);
    float d0 = v0 - mean, d1 = v1 - mean;
    float q = d0 * d0 + d1 * d1;
    #pragma unroll
    for (int o = 32; o; o >>= 1) q += __shfl_xor(q, o);
    float rstd = rsqrtf(q * (1.0f / 128.0f) + 1e-5f);
    float y0 = d0 * rstd * g[l] + bt[l];
    float y1 = d1 * rstd * g[l + 64] + bt[l + 64];
    size_t r0 = (size_t)row * IN0;
    unsigned short h0 = bfh(y0), lo0 = bfh(y0 - bf2f(h0));
    unsigned short h1 = bfh(y1), lo1 = bfh(y1 - bf2f(h1));
    X0h[r0 + 32 + l] = h0; X0l[r0 + 32 + l] = lo0;
    X0h[r0 + 96 + l] = h1; X0l[r0 + 96 + l] = lo1;
    if (l < LATENT) {
        float zv = z[(size_t)row * LATENT + l];
        unsigned short zh = bfh(zv), zl = bfh(zv - bf2f(zh));
        X0h[r0 + l] = zh; X0l[r0 + l] = zl;
        size_t r1 = (size_t)row * INTER;
        X1h[r1 + l] = zh; X1l[r1 + l] = zl;
        X2h[r1 + l] = zh; X2l[r1 + l] = zl;
    }
}

// ---------- MoE layer v3: 8 waves, A in VGPRs, B-only LDS (3 bufs), 1 barrier/phase ----------
// Wave (wm, we): rows brow+wm*32..+32, cols bn..+32, experts {2we, 2we+1}.
// Phase t: vmcnt(stage t done) -> barrier -> issue stage(t+2) -> 8 ds_read + 24 MFMA.
// Epilogue: cf-scaled partials reduced across we-waves via LDS.
template<int KS>
__global__ __launch_bounds__(512, 2) void k_moe_epar3(
    const unsigned short* __restrict__ Ah, const unsigned short* __restrict__ Al,
    const unsigned short* __restrict__ Bh, const unsigned short* __restrict__ Bl,
    const float* __restrict__ bias,   // [8][256]
    const float* __restrict__ coeff,  // [B][8]
    unsigned short* __restrict__ outH, unsigned short* __restrict__ outL)
{
    constexpr int K = KS * 32;
    __shared__ __align__(16) char smem[98304];   // 3 B-bufs x 32KB
    __shared__ float cf_s[64][8];

    const int tid = threadIdx.x, wid = tid >> 6, l = tid & 63;
    const int wm = wid & 1, we = wid >> 1;
    const int brow = (blockIdx.x >> 3) * 64;
    const int bn   = (blockIdx.x & 7) * 32;      // each XCD -> one col slice

    cf_s[tid >> 3][tid & 7] = coeff[(size_t)(brow + (tid >> 3)) * 8 + (tid & 7)];

    // ---- A -> VGPRs (MFMA frag layout: row = l&15, k-chunk = l>>4) ----
    const unsigned short* Arh = Ah + (size_t)(brow + wm * 32 + (l & 15)) * K + (l >> 4) * 8;
    const unsigned short* Arl = Al + (size_t)(brow + wm * 32 + (l & 15)) * K + (l >> 4) * 8;
    i32x4 a_h[KS][2], a_l[KS][2];
    #pragma unroll
    for (int ks = 0; ks < KS; ++ks)
        #pragma unroll
        for (int mf = 0; mf < 2; ++mf) {
            a_h[ks][mf] = *(const i32x4*)(Arh + (size_t)mf * 16 * K + ks * 32);
            a_l[ks][mf] = *(const i32x4*)(Arl + (size_t)mf * 16 * K + ks * 32);
        }
    __builtin_amdgcn_sched_barrier(0);   // keep A loads before stage loads (vmcnt counting)

    // ---- B staging: 32 x 1KB units per buf; wave stages units 4*wid..4*wid+3 ----
    const int swz = (((l & 3) ^ ((l >> 3) & 3)) << 3);
    const int rq  = l >> 2;
    const unsigned short* sBp[4];
    #pragma unroll
    for (int j = 0; j < 4; ++j) {
        const int u = wid * 4 + j, e = u >> 2, h = (u >> 1) & 1, g = u & 1;
        sBp[j] = (h ? Bl : Bh) + (size_t)(e * HID + bn + g * 16 + rq) * K + swz;
    }
    auto stage = [&](int t, int bi) {
        char* buf = smem + bi * 32768;
        #pragma unroll
        for (int j = 0; j < 4; ++j)
            gload16(sBp[j] + t * 32, buf + (wid * 4 + j) * 1024);
    };

    stage(0, 0);
    stage(1, 1);
    asm volatile("s_waitcnt vmcnt(8)" ::: "memory");   // A regs complete (2 stages newer)
    #pragma unroll
    for (int ks = 0; ks < KS; ++ks)
        #pragma unroll
        for (int mf = 0; mf < 2; ++mf) {               // launder A from waitcnt pass
            asm volatile("" : "+v"(a_h[ks][mf]));
            asm volatile("" : "+v"(a_l[ks][mf]));
        }
    __syncthreads();   // cf_s visible

    const int rdo = ((l & 15) << 6) + (((l >> 4) ^ ((l >> 1) & 3)) << 4);
    f32x4 acc[2][2][2];   // [e2][mf][nf]
    #pragma unroll
    for (int e2 = 0; e2 < 2; ++e2)
        #pragma unroll
        for (int mf = 0; mf < 2; ++mf)
            #pragma unroll
            for (int nf = 0; nf < 2; ++nf) acc[e2][mf][nf] = (f32x4){0.f, 0.f, 0.f, 0.f};

    for (int t = 0; t < KS; ++t) {
        if (t + 1 < KS) { asm volatile("s_waitcnt vmcnt(4)" ::: "memory"); }
        else            { asm volatile("s_waitcnt vmcnt(0)" ::: "memory"); }
        __builtin_amdgcn_s_barrier();
        if (t + 2 < KS) stage(t + 2, (t + 2) % 3);
        __builtin_amdgcn_sched_barrier(0);

        const char* bp = smem + (t % 3) * 32768;
        __builtin_amdgcn_s_setprio(1);
        #pragma unroll
        for (int e2 = 0; e2 < 2; ++e2) {
            const char* be = bp + (2 * we + e2) * 4096;
            short8 bh0 = *(const short8*)(be + rdo);
            short8 bh1 = *(const short8*)(be + 1024 + rdo);
            short8 bl0 = *(const short8*)(be + 2048 + rdo);
            short8 bl1 = *(const short8*)(be + 3072 + rdo);
            #pragma unroll
            for (int mf = 0; mf < 2; ++mf) {
                acc[e2][mf][0] = __builtin_amdgcn_mfma_f32_16x16x32_bf16(as_s8(a_h[t][mf]), bh0, acc[e2][mf][0], 0, 0, 0);
                acc[e2][mf][0] = __builtin_amdgcn_mfma_f32_16x16x32_bf16(as_s8(a_h[t][mf]), bl0, acc[e2][mf][0], 0, 0, 0);
                acc[e2][mf][0] = __builtin_amdgcn_mfma_f32_16x16x32_bf16(as_s8(a_l[t][mf]), bh0, acc[e2][mf][0], 0, 0, 0);
                acc[e2][mf][1] = __builtin_amdgcn_mfma_f32_16x16x32_bf16(as_s8(a_h[t][mf]), bh1, acc[e2][mf][1], 0, 0, 0);
                acc[e2][mf][1] = __builtin_amdgcn_mfma_f32_16x16x32_bf16(as_s8(a_h[t][mf]), bl1, acc[e2][mf][1], 0, 0, 0);
                acc[e2][mf][1] = __builtin_amdgcn_mfma_f32_16x16x32_bf16(as_s8(a_l[t][mf]), bh1, acc[e2][mf][1], 0, 0, 0);
            }
        }
        __builtin_amdgcn_s_setprio(0);
    }
    __syncthreads();   // all MFMAs done everywhere -> safe to overlay smem

    // ---- epilogue: fold (acc+bias)*cf per wave, reduce across the 4 we-waves ----
    const int e0 = 2 * we, e1 = 2 * we + 1;
    float bv0[2], bv1[2];
    #pragma unroll
    for (int nf = 0; nf < 2; ++nf) {
        bv0[nf] = bias[e0 * HID + bn + nf * 16 + (l & 15)];
        bv1[nf] = bias[e1 * HID + bn + nf * 16 + (l & 15)];
    }
    float* red = (float*)smem;   // [2 wm][4 we][32 rows][36]
    #pragma unroll
    for (int mf = 0; mf < 2; ++mf) {
        #pragma unroll
        for (int r = 0; r < 4; ++r) {
            const int r32 = mf * 16 + ((l >> 4) << 2) + r;
            float c0 = cf_s[wm * 32 + r32][e0];
            float c1 = cf_s[wm * 32 + r32][e1];
            #pragma unroll
            for (int nf = 0; nf < 2; ++nf) {
                float s = (acc[0][mf][nf][r] + bv0[nf]) * c0
                        + (acc[1][mf][nf][r] + bv1[nf]) * c1;
                red[(wm * 4 + we) * 1152 + r32 * 36 + nf * 16 + (l & 15)] = s;
            }
        }
    }
    __syncthreads();

    const int row = tid >> 3, c0_ = (tid & 7) * 4;
    const int wm2 = row >> 5, r32 = row & 31;
    f32x4 s4 = {0.f, 0.f, 0.f, 0.f};
    #pragma unroll
    for (int w = 0; w < 4; ++w)
        s4 += *(const f32x4*)&red[(wm2 * 4 + w) * 1152 + r32 * 36 + c0_];
    unsigned short hh[4], ll[4];
    #pragma unroll
    for (int j = 0; j < 4; ++j) {
        float ev = elu1(s4[j]);
        hh[j] = bfh(ev); ll[j] = bfh(ev - bf2f(hh[j]));
    }
    size_t o = (size_t)(brow + row) * INTER + 32 + bn + c0_;
    *(short4v*)&outH[o] = *(const short4v*)hh;
    *(short4v*)&outL[o] = *(const short4v*)ll;
}

// ---------- small GEMM: 64-row / 4-wave, weight-stationary, no K-loop barriers ----------
template<int KS, int NCOL, int OUTM, int SOUT, int OFS>
__global__ __launch_bounds__(256, 2) void k_small64(
    const unsigned short* __restrict__ Ah, const unsigned short* __restrict__ Al,
    const unsigned short* __restrict__ Bh, const unsigned short* __restrict__ Bl,
    const float* __restrict__ bias,
    float* __restrict__ outF, unsigned short* __restrict__ outH,
    unsigned short* __restrict__ outL)
{
    constexpr int K  = KS * 32;
    constexpr int NG = NCOL / 16;
    constexpr int CT = 128 / NCOL;
    __shared__ __align__(16) char smem[KS * NG * 2048];

    const int tid = threadIdx.x, wid = tid >> 6, l = tid & 63;
    const int brow = (blockIdx.x / CT) * 64 + wid * 16;
    const int bn   = (blockIdx.x % CT) * NCOL;

    const unsigned short* Arh = Ah + (size_t)(brow + (l & 15)) * K + (l >> 4) * 8;
    const unsigned short* Arl = Al + (size_t)(brow + (l & 15)) * K + (l >> 4) * 8;
    i32x4 ah_[KS], al_[KS];
    #pragma unroll
    for (int ks = 0; ks < KS; ++ks) {
        ah_[ks] = *(const i32x4*)(Arh + ks * 32);
        al_[ks] = *(const i32x4*)(Arl + ks * 32);
    }

    const int swz = (((l & 3) ^ ((l >> 3) & 3)) << 3);
    const int rq  = l >> 2;
    #pragma unroll
    for (int p = 0; p < KS * NG; ++p) {
        if ((p & 3) != wid) continue;
        const int ks = p / NG, g = p % NG;
        const size_t so = (size_t)(bn + g * 16 + rq) * K + ks * 32 + swz;
        gload16(Bh + so, smem + p * 2048);
        gload16(Bl + so, smem + p * 2048 + 1024);
    }
    __syncthreads();

    const int rdo = ((l & 15) << 6) + (((l >> 4) ^ ((l >> 1) & 3)) << 4);
    f32x4 acc[NG];
    #pragma unroll
    for (int nf = 0; nf < NG; ++nf) {
        float bv = bias[bn + nf * 16 + (l & 15)];
        acc[nf] = (f32x4){bv, bv, bv, bv};
    }
    #pragma unroll
    for (int ks = 0; ks < KS; ++ks)
        #pragma unroll
        for (int nf = 0; nf < NG; ++nf) {
            const char* bp = smem + (size_t)(ks * NG + nf) * 2048;
            short8 bh = *(const short8*)(bp + rdo);
            short8 bl = *(const short8*)(bp + 1024 + rdo);
            acc[nf] = __builtin_amdgcn_mfma_f32_16x16x32_bf16(as_s8(ah_[ks]), bh, acc[nf], 0, 0, 0);
            acc[nf] = __builtin_amdgcn_mfma_f32_16x16x32_bf16(as_s8(ah_[ks]), bl, acc[nf], 0, 0, 0);
            acc[nf] = __builtin_amdgcn_mfma_f32_16x16x32_bf16(as_s8(al_[ks]), bh, acc[nf], 0, 0, 0);
        }

    #pragma unroll
    for (int nf = 0; nf < NG; ++nf)
        #pragma unroll
        for (int r = 0; r < 4; ++r) {
            const int row = brow + ((l >> 4) << 2) + r;
            const int col = bn + nf * 16 + (l & 15);
            size_t o = (size_t)row * SOUT + OFS + col;
            float v = acc[nf][r];
            if (OUTM == 0) {
                outF[o] = v;
            } else if (OUTM == 2) {
                outF[o] = elu1(v);
            } else {
                float ev = elu1(v);
                unsigned short h = bfh(ev);
                unsigned short lo = bfh(ev - bf2f(h));
                outH[o] = h; outL[o] = lo;
            }
        }
}

// ---------- gate output layer + softmax over 8 experts (one wave/row) ----------
__global__ __launch_bounds__(256) void k_gate_out(
    const float* __restrict__ G2, const float* __restrict__ g2w,
    const float* __restrict__ g2b, float* __restrict__ coeff)
{
    __shared__ float wt[NE][GH];
    int tid = threadIdx.x;
    for (int idx = tid; idx < GH * NE; idx += 256) {
        int k = idx >> 3, e = idx & 7;
        wt[e][k] = g2w[idx];
    }
    __syncthreads();
    int row  = (blockIdx.x * 256 + tid) >> 6;
    int lane = tid & 63;
    if (row >= B_) return;
    float a0 = G2[(size_t)row * GH + lane];
    float a1 = G2[(size_t)row * GH + 64 + lane];
    float p[NE];
    #pragma unroll
    for (int e = 0; e < NE; ++e)
        p[e] = a0 * wt[e][lane] + a1 * wt[e][lane + 64];
    #pragma unroll
    for (int o = 32; o; o >>= 1) {
        #pragma unroll
        for (int e = 0; e < NE; ++e) p[e] += __shfl_xor(p[e], o);
    }
    float mx = -1e30f;
    #pragma unroll
    for (int e = 0; e < NE; ++e) { p[e] += g2b[e]; mx = fmaxf(mx, p[e]); }
    float s = 0.0f;
    #pragma unroll
    for (int e = 0; e < NE; ++e) { p[e] = expf(p[e] - mx); s += p[e]; }
    float inv = 1.0f / s;
    if (lane == 0) {
        #pragma unroll
        for (int e = 0; e < NE; ++e) coeff[(size_t)row * NE + e] = p[e] * inv;
    }
}

// ---------- final mix: out[b,o] = sum_e cf[b,e] * P[b, e*16+o] ----------
__global__ __launch_bounds__(256) void k_mix(
    const float* __restrict__ P, const float* __restrict__ cf, float* __restrict__ out)
{
    int id = blockIdx.x * 256 + threadIdx.x;
    if (id >= B_ * ACTD) return;
    int b = id >> 4, o = id & 15;
    const float* pr = P + (size_t)b * 128 + o;
    const float* cr = cf + (size_t)b * 8;
    float s = 0.f;
    #pragma unroll
    for (int e = 0; e < 8; ++e) s += cr[e] * pr[e * 16];
    out[id] = s;
}

extern "C" void kernel_launch(void* const* d_in, const int* in_sizes, int n_in,
                              void* d_out, int out_size, void* d_ws, size_t ws_size,
                              hipStream_t stream)
{
    (void)in_sizes; (void)n_in; (void)out_size; (void)ws_size;
    const float* z   = (const float*)d_in[0];
    const float* c   = (const float*)d_in[1];
    const float* w0  = (const float*)d_in[2];
    const float* b0  = (const float*)d_in[3];
    const float* w1  = (const float*)d_in[4];
    const float* b1  = (const float*)d_in[5];
    const float* w2  = (const float*)d_in[6];
    const float* b2  = (const float*)d_in[7];
    const float* g0w = (const float*)d_in[8];
    const float* g0b = (const float*)d_in[9];
    const float* g1w = (const float*)d_in[10];
    const float* g1b = (const float*)d_in[11];
    const float* g2w = (const float*)d_in[12];
    const float* g2b = (const float*)d_in[13];
    const float* lng = (const float*)d_in[14];
    const float* lnb = (const float*)d_in[15];
    float* out = (float*)d_out;

    char* p = (char*)d_ws;
    auto alloc = [&](size_t n) { char* r = p; p += (n + 255) & ~(size_t)255; return r; };
    unsigned short* X0h = (unsigned short*)alloc((size_t)B_ * IN0 * 2);
    unsigned short* X0l = (unsigned short*)alloc((size_t)B_ * IN0 * 2);
    unsigned short* X1h = (unsigned short*)alloc((size_t)B_ * INTER * 2);
    unsigned short* X1l = (unsigned short*)alloc((size_t)B_ * INTER * 2);
    unsigned short* X2h = (unsigned short*)alloc((size_t)B_ * INTER * 2);
    unsigned short* X2l = (unsigned short*)alloc((size_t)B_ * INTER * 2);
    unsigned short* G1h = (unsigned short*)alloc((size_t)B_ * GH * 2);
    unsigned short* G1l = (unsigned short*)alloc((size_t)B_ * GH * 2);
    float* G2f = (float*)alloc((size_t)B_ * GH * 4);      // reused as P2 after gate_out
    float* cf  = (float*)alloc((size_t)B_ * NE * 4);
    unsigned short* T0h = (unsigned short*)alloc((size_t)NE * IN0 * HID * 2);
    unsigned short* T0l = (unsigned short*)alloc((size_t)NE * IN0 * HID * 2);
    unsigned short* T1h = (unsigned short*)alloc((size_t)NE * INTER * HID * 2);
    unsigned short* T1l = (unsigned short*)alloc((size_t)NE * INTER * HID * 2);
    unsigned short* T2h = (unsigned short*)alloc((size_t)NE * INTER * ACTD * 2);
    unsigned short* T2l = (unsigned short*)alloc((size_t)NE * INTER * ACTD * 2);
    unsigned short* G0Th = (unsigned short*)alloc((size_t)IN0 * GH * 2);
    unsigned short* G0Tl = (unsigned short*)alloc((size_t)IN0 * GH * 2);
    unsigned short* G1Th = (unsigned short*)alloc((size_t)GH * GH * 2);
    unsigned short* G1Tl = (unsigned short*)alloc((size_t)GH * GH * 2);
    float* P2 = G2f;

    k_prep_g<<<dim3(484), dim3(256), 0, stream>>>(w0, w1, w2, g0w, g1w,
        T0h, T0l, T1h, T1l, T2h, T2l, G0Th, G0Tl, G1Th, G1Tl);
    k_ln_concat2<<<dim3(B_ / 4), dim3(256), 0, stream>>>(z, c, lng, lnb,
        X0h, X0l, X1h, X1l, X2h, X2l);

    // gate MLP: X0 -> G1 (bf16 hi/lo) -> G2f (fp32+elu) -> coeff
    k_small64<5, 64, 1, 128, 0><<<dim3(256), dim3(256), 0, stream>>>(
        X0h, X0l, G0Th, G0Tl, g0b, nullptr, G1h, G1l);
    k_small64<4, 64, 2, 128, 0><<<dim3(256), dim3(256), 0, stream>>>(
        G1h, G1l, G1Th, G1Tl, g1b, G2f, nullptr, nullptr);
    k_gate_out<<<dim3(B_ / 4), dim3(256), 0, stream>>>(G2f, g2w, g2b, cf);

    // expert layers: 8-wave blocks, A in VGPRs, B-only LDS pipeline
    k_moe_epar3<5><<<dim3(1024), dim3(512), 0, stream>>>(
        X0h, X0l, T0h, T0l, b0, cf, X1h, X1l);
    k_moe_epar3<9><<<dim3(1024), dim3(512), 0, stream>>>(
        X1h, X1l, T1h, T1l, b1, cf, X2h, X2l);
    // final layer as plain GEMM over N = E*16 = 128, then coeff-mix
    k_small64<9, 32, 0, 128, 0><<<dim3(512), dim3(256), 0, stream>>>(
        X2h, X2l, T2h, T2l, b2, P2, nullptr, nullptr);
    k_mix<<<dim3(B_ * ACTD / 256), dim3(256), 0, stream>>>(P2, cf, out);
}

// Round 8
// 116.810 us; speedup vs baseline: 1.1982x; 1.1982x over previous
//
#include <hip/hip_runtime.h>
#include <hip/hip_bf16.h>
#include <math.h>

#define B_     8192
#define LATENT 32
#define CIN    128
#define HID    256
#define ACTD   16
#define NE     8
#define GH     128
#define IN0    160   // LATENT + CIN
#define INTER  288   // HID + LATENT

typedef __attribute__((ext_vector_type(8))) short short8;
typedef __attribute__((ext_vector_type(4))) float f32x4;
typedef __attribute__((ext_vector_type(4))) int   i32x4;

__device__ __forceinline__ float elu1(float x) { return x > 0.0f ? x : expm1f(x); }

__device__ __forceinline__ unsigned short bfh(float v) {
    __hip_bfloat16 b = __float2bfloat16(v);
    return *reinterpret_cast<unsigned short*>(&b);
}
__device__ __forceinline__ float bf2f(unsigned short u) {
    __hip_bfloat16 b;
    *reinterpret_cast<unsigned short*>(&b) = u;
    return __bfloat162float(b);
}
__device__ __forceinline__ void gload16(const unsigned short* g, const char* lds) {
    __builtin_amdgcn_global_load_lds((const __attribute__((address_space(1))) void*)g,
                                     (__attribute__((address_space(3))) void*)lds, 16, 0, 0);
}
__device__ __forceinline__ short8 as_s8(i32x4 v) {
    union U { i32x4 a; short8 b; } u; u.a = v; return u.b;
}

// ---------- prep (gather form): coalesced short8 writes, strided reads ----------
__global__ __launch_bounds__(256) void k_prep_g(
    const float* __restrict__ w0, const float* __restrict__ w1, const float* __restrict__ w2,
    const float* __restrict__ g0w, const float* __restrict__ g1w,
    unsigned short* __restrict__ T0h, unsigned short* __restrict__ T0l,
    unsigned short* __restrict__ T1h, unsigned short* __restrict__ T1l,
    unsigned short* __restrict__ T2h, unsigned short* __restrict__ T2l,
    unsigned short* __restrict__ G0h, unsigned short* __restrict__ G0l,
    unsigned short* __restrict__ G1h, unsigned short* __restrict__ G1l)
{
    int g = blockIdx.x * 256 + threadIdx.x;
    const float* src; int stride; size_t dst; unsigned short *H, *L;
    if (g < 40960) {                       // T0: [8][160][256] -> [8*256][160]
        int e = g / 5120, r = g % 5120, o = r / 20, i0 = (r % 20) * 8;
        src = w0 + ((size_t)e * 160 + i0) * 256 + o; stride = 256;
        dst = ((size_t)e * 256 + o) * 160 + i0; H = T0h; L = T0l;
    } else if (g < 114688) {               // T1: [8][288][256] -> [8*256][288]
        int t = g - 40960;
        int e = t / 9216, r = t % 9216, o = r / 36, i0 = (r % 36) * 8;
        src = w1 + ((size_t)e * 288 + i0) * 256 + o; stride = 256;
        dst = ((size_t)e * 256 + o) * 288 + i0; H = T1h; L = T1l;
    } else if (g < 119296) {               // T2: [8][288][16] -> [8*16][288]
        int t = g - 114688;
        int e = t / 576, r = t % 576, o = r / 36, i0 = (r % 36) * 8;
        src = w2 + ((size_t)e * 288 + i0) * 16 + o; stride = 16;
        dst = ((size_t)e * 16 + o) * 288 + i0; H = T2h; L = T2l;
    } else if (g < 121856) {               // G0: [160][128] -> [128][160]
        int t = g - 119296;
        int o = t / 20, i0 = (t % 20) * 8;
        src = g0w + (size_t)i0 * 128 + o; stride = 128;
        dst = (size_t)o * 160 + i0; H = G0h; L = G0l;
    } else if (g < 123904) {               // G1: [128][128] -> [128][128]
        int t = g - 121856;
        int o = t / 16, i0 = (t % 16) * 8;
        src = g1w + (size_t)i0 * 128 + o; stride = 128;
        dst = (size_t)o * 128 + i0; H = G1h; L = G1l;
    } else return;
    unsigned short hh[8], ll[8];
    #pragma unroll
    for (int j = 0; j < 8; ++j) {
        float v = src[(size_t)j * stride];
        hh[j] = bfh(v);
        ll[j] = bfh(v - bf2f(hh[j]));
    }
    *(short8*)&H[dst] = *(const short8*)hh;
    *(short8*)&L[dst] = *(const short8*)ll;
}

// ---------- LayerNorm + concat, split to hi/lo; also seed z into X1/X2 ----------
__global__ __launch_bounds__(256) void k_ln_concat2(
    const float* __restrict__ z, const float* __restrict__ c,
    const float* __restrict__ g, const float* __restrict__ bt,
    unsigned short* __restrict__ X0h, unsigned short* __restrict__ X0l,
    unsigned short* __restrict__ X1h, unsigned short* __restrict__ X1l,
    unsigned short* __restrict__ X2h, unsigned short* __restrict__ X2l)
{
    int gid = blockIdx.x * 256 + threadIdx.x;
    int row = gid >> 6;
    int l = threadIdx.x & 63;
    if (row >= B_) return;
    const float* cr = c + (size_t)row * CIN;
    float v0 = cr[l], v1 = cr[l + 64];
    float s = v0 + v1;
    #pragma unroll
    for (int o = 32; o; o >>= 1) s += __shfl_xor(s, o);
    float mean = s * (1.0f / 128.0f);
    float d0 = v0 - mean, d1 = v1 - mean;
    float q = d0 * d0 + d1 * d1;
    #pragma unroll
    for (int o = 32; o; o >>= 1) q += __shfl_xor(q, o);
    float rstd = rsqrtf(q * (1.0f / 128.0f) + 1e-5f);
    float y0 = d0 * rstd * g[l] + bt[l];
    float y1 = d1 * rstd * g[l + 64] + bt[l + 64];
    size_t r0 = (size_t)row * IN0;
    unsigned short h0 = bfh(y0), lo0 = bfh(y0 - bf2f(h0));
    unsigned short h1 = bfh(y1), lo1 = bfh(y1 - bf2f(h1));
    X0h[r0 + 32 + l] = h0; X0l[r0 + 32 + l] = lo0;
    X0h[r0 + 96 + l] = h1; X0l[r0 + 96 + l] = lo1;
    if (l < LATENT) {
        float zv = z[(size_t)row * LATENT + l];
        unsigned short zh = bfh(zv), zl = bfh(zv - bf2f(zh));
        X0h[r0 + l] = zh; X0l[r0 + l] = zl;
        size_t r1 = (size_t)row * INTER;
        X1h[r1 + l] = zh; X1l[r1 + l] = zl;
        X2h[r1 + l] = zh; X2l[r1 + l] = zl;
    }
}

// ---------- MoE layer v4: e-sequential, A in VGPRs, tiny shared B tiles ----------
// Block: 256 thr / 4 waves; tile 128 rows x 32 cols; wave owns 32 rows (full cols).
// A (its 32 rows, whole K, hi/lo) lives in VGPRs -- loaded ONCE, reused for all
// 8 experts. Per phase (e,ks): block stages a 4KB B tile (1 gload16/lane) into
// one of 4 LDS bufs; each wave: 4 ds_read + 12 MFMA. Counted vmcnt(2), one
// barrier/phase. Per-expert fold accT += cf_e*(accW+bias_e) -- per-wave only.
template<int KS>
__global__ __launch_bounds__(256, 2) void k_moe_seq(
    const unsigned short* __restrict__ Ah, const unsigned short* __restrict__ Al,
    const unsigned short* __restrict__ Bh, const unsigned short* __restrict__ Bl,
    const float* __restrict__ bias,   // [8][256]
    const float* __restrict__ coeff,  // [B][8]
    unsigned short* __restrict__ outH, unsigned short* __restrict__ outL)
{
    constexpr int K = KS * 32;
    constexpr int T = KS * NE;
    __shared__ __align__(16) char sB[4][4096];   // 4 bufs x 4KB
    __shared__ float cf_s[8][128];
    __shared__ float bias_s[8][32];

    const int tid = threadIdx.x, wid = tid >> 6, l = tid & 63;
    const int brow = (blockIdx.x >> 3) * 128;
    const int bn   = (blockIdx.x & 7) * 32;      // XCD -> one col slice

    // cf / bias -> LDS
    for (int idx = tid; idx < 1024; idx += 256)
        cf_s[idx & 7][idx >> 3] = coeff[(size_t)(brow + (idx >> 3)) * 8 + (idx & 7)];
    if (tid < 256) {
        int e = tid >> 5, o = tid & 31;
        bias_s[e][o] = bias[e * HID + bn + o];
    }

    // ---- A -> VGPRs (frag layout: row = l&15, k-chunk = l>>4), whole K ----
    const unsigned short* Arh = Ah + (size_t)(brow + wid * 32 + (l & 15)) * K + (l >> 4) * 8;
    const unsigned short* Arl = Al + (size_t)(brow + wid * 32 + (l & 15)) * K + (l >> 4) * 8;
    i32x4 a_h[KS][2], a_l[KS][2];
    #pragma unroll
    for (int ks = 0; ks < KS; ++ks)
        #pragma unroll
        for (int mf = 0; mf < 2; ++mf) {
            a_h[ks][mf] = *(const i32x4*)(Arh + (size_t)mf * 16 * K + ks * 32);
            a_l[ks][mf] = *(const i32x4*)(Arl + (size_t)mf * 16 * K + ks * 32);
        }

    // ---- B stage setup: wave wid writes unit wid (1KB) of the 4KB tile ----
    // unit u: g = u&1 (16-col group), h = u>>1 (0=hi, 1=lo)
    const int swz = (((l & 3) ^ ((l >> 3) & 3)) << 3);
    const int rq  = l >> 2;
    const int gu = wid & 1, hu = wid >> 1;
    const unsigned short* sBp =
        (hu ? Bl : Bh) + (size_t)(bn + gu * 16 + rq) * K + swz;
    auto stage = [&](int tt) {
        const int e = tt / KS, ks = tt - e * KS;
        gload16(sBp + (size_t)e * HID * K + ks * 32, sB[tt & 3] + wid * 1024);
    };

    stage(0); stage(1); stage(2);
    __syncthreads();   // full drain (A + 3 stages + cf/bias); pipeline refills

    #pragma unroll
    for (int ks = 0; ks < KS; ++ks)
        #pragma unroll
        for (int mf = 0; mf < 2; ++mf) {   // launder A from the waitcnt pass
            asm volatile("" : "+v"(a_h[ks][mf]));
            asm volatile("" : "+v"(a_l[ks][mf]));
        }

    const int rdo = ((l & 15) << 6) + (((l >> 4) ^ ((l >> 1) & 3)) << 4);
    f32x4 accW[2][2], accT[2][2];
    #pragma unroll
    for (int mf = 0; mf < 2; ++mf)
        #pragma unroll
        for (int nf = 0; nf < 2; ++nf) {
            accW[mf][nf] = (f32x4){0.f, 0.f, 0.f, 0.f};
            accT[mf][nf] = (f32x4){0.f, 0.f, 0.f, 0.f};
        }

    for (int e = 0; e < NE; ++e) {
        #pragma unroll
        for (int ks = 0; ks < KS; ++ks) {
            const int tt = e * KS + ks;
            const int rem = T - 1 - tt;
            if (rem >= 3)      { asm volatile("s_waitcnt vmcnt(2)" ::: "memory"); }
            else if (rem == 2) { asm volatile("s_waitcnt vmcnt(2)" ::: "memory"); }
            else if (rem == 1) { asm volatile("s_waitcnt vmcnt(1)" ::: "memory"); }
            else               { asm volatile("s_waitcnt vmcnt(0)" ::: "memory"); }
            __builtin_amdgcn_s_barrier();
            if (tt + 3 < T) stage(tt + 3);
            __builtin_amdgcn_sched_barrier(0);

            const char* bp = sB[tt & 3];
            short8 bqh[2], bql[2];
            #pragma unroll
            for (int nf = 0; nf < 2; ++nf) {
                bqh[nf] = *(const short8*)(bp + nf * 1024 + rdo);
                bql[nf] = *(const short8*)(bp + (2 + nf) * 1024 + rdo);
            }
            __builtin_amdgcn_s_setprio(1);
            #pragma unroll
            for (int mf = 0; mf < 2; ++mf)
                #pragma unroll
                for (int nf = 0; nf < 2; ++nf) {
                    accW[mf][nf] = __builtin_amdgcn_mfma_f32_16x16x32_bf16(as_s8(a_h[ks][mf]), bqh[nf], accW[mf][nf], 0, 0, 0);
                    accW[mf][nf] = __builtin_amdgcn_mfma_f32_16x16x32_bf16(as_s8(a_h[ks][mf]), bql[nf], accW[mf][nf], 0, 0, 0);
                    accW[mf][nf] = __builtin_amdgcn_mfma_f32_16x16x32_bf16(as_s8(a_l[ks][mf]), bqh[nf], accW[mf][nf], 0, 0, 0);
                }
            __builtin_amdgcn_s_setprio(0);
        }
        // per-expert fold (per-wave, exact fp32)
        #pragma unroll
        for (int mf = 0; mf < 2; ++mf) {
            f32x4 cv = *(const f32x4*)&cf_s[e][wid * 32 + mf * 16 + ((l >> 4) << 2)];
            #pragma unroll
            for (int nf = 0; nf < 2; ++nf) {
                float bv = bias_s[e][nf * 16 + (l & 15)];
                #pragma unroll
                for (int r = 0; r < 4; ++r) {
                    accT[mf][nf][r] += cv[r] * (accW[mf][nf][r] + bv);
                    accW[mf][nf][r] = 0.0f;
                }
            }
        }
    }

    #pragma unroll
    for (int mf = 0; mf < 2; ++mf)
        #pragma unroll
        for (int nf = 0; nf < 2; ++nf)
            #pragma unroll
            for (int r = 0; r < 4; ++r) {
                const int row = brow + wid * 32 + mf * 16 + ((l >> 4) << 2) + r;
                const int col = bn + nf * 16 + (l & 15);
                size_t o = (size_t)row * INTER + 32 + col;
                float ev = elu1(accT[mf][nf][r]);
                unsigned short h = bfh(ev);
                unsigned short lo = bfh(ev - bf2f(h));
                outH[o] = h; outL[o] = lo;
            }
}

// ---------- small GEMM: 64-row / 4-wave, weight-stationary, no K-loop barriers ----------
template<int KS, int NCOL, int OUTM, int SOUT, int OFS>
__global__ __launch_bounds__(256, 2) void k_small64(
    const unsigned short* __restrict__ Ah, const unsigned short* __restrict__ Al,
    const unsigned short* __restrict__ Bh, const unsigned short* __restrict__ Bl,
    const float* __restrict__ bias,
    float* __restrict__ outF, unsigned short* __restrict__ outH,
    unsigned short* __restrict__ outL)
{
    constexpr int K  = KS * 32;
    constexpr int NG = NCOL / 16;
    constexpr int CT = 128 / NCOL;
    __shared__ __align__(16) char smem[KS * NG * 2048];

    const int tid = threadIdx.x, wid = tid >> 6, l = tid & 63;
    const int brow = (blockIdx.x / CT) * 64 + wid * 16;
    const int bn   = (blockIdx.x % CT) * NCOL;

    const unsigned short* Arh = Ah + (size_t)(brow + (l & 15)) * K + (l >> 4) * 8;
    const unsigned short* Arl = Al + (size_t)(brow + (l & 15)) * K + (l >> 4) * 8;
    i32x4 ah_[KS], al_[KS];
    #pragma unroll
    for (int ks = 0; ks < KS; ++ks) {
        ah_[ks] = *(const i32x4*)(Arh + ks * 32);
        al_[ks] = *(const i32x4*)(Arl + ks * 32);
    }

    const int swz = (((l & 3) ^ ((l >> 3) & 3)) << 3);
    const int rq  = l >> 2;
    #pragma unroll
    for (int p = 0; p < KS * NG; ++p) {
        if ((p & 3) != wid) continue;
        const int ks = p / NG, g = p % NG;
        const size_t so = (size_t)(bn + g * 16 + rq) * K + ks * 32 + swz;
        gload16(Bh + so, smem + p * 2048);
        gload16(Bl + so, smem + p * 2048 + 1024);
    }
    __syncthreads();

    const int rdo = ((l & 15) << 6) + (((l >> 4) ^ ((l >> 1) & 3)) << 4);
    f32x4 acc[NG];
    #pragma unroll
    for (int nf = 0; nf < NG; ++nf) {
        float bv = bias[bn + nf * 16 + (l & 15)];
        acc[nf] = (f32x4){bv, bv, bv, bv};
    }
    #pragma unroll
    for (int ks = 0; ks < KS; ++ks)
        #pragma unroll
        for (int nf = 0; nf < NG; ++nf) {
            const char* bp = smem + (size_t)(ks * NG + nf) * 2048;
            short8 bh = *(const short8*)(bp + rdo);
            short8 bl = *(const short8*)(bp + 1024 + rdo);
            acc[nf] = __builtin_amdgcn_mfma_f32_16x16x32_bf16(as_s8(ah_[ks]), bh, acc[nf], 0, 0, 0);
            acc[nf] = __builtin_amdgcn_mfma_f32_16x16x32_bf16(as_s8(ah_[ks]), bl, acc[nf], 0, 0, 0);
            acc[nf] = __builtin_amdgcn_mfma_f32_16x16x32_bf16(as_s8(al_[ks]), bh, acc[nf], 0, 0, 0);
        }

    #pragma unroll
    for (int nf = 0; nf < NG; ++nf)
        #pragma unroll
        for (int r = 0; r < 4; ++r) {
            const int row = brow + ((l >> 4) << 2) + r;
            const int col = bn + nf * 16 + (l & 15);
            size_t o = (size_t)row * SOUT + OFS + col;
            float v = acc[nf][r];
            if (OUTM == 0) {
                outF[o] = v;
            } else if (OUTM == 2) {
                outF[o] = elu1(v);
            } else {
                float ev = elu1(v);
                unsigned short h = bfh(ev);
                unsigned short lo = bfh(ev - bf2f(h));
                outH[o] = h; outL[o] = lo;
            }
        }
}

// ---------- gate output layer + softmax over 8 experts (one wave/row) ----------
__global__ __launch_bounds__(256) void k_gate_out(
    const float* __restrict__ G2, const float* __restrict__ g2w,
    const float* __restrict__ g2b, float* __restrict__ coeff)
{
    __shared__ float wt[NE][GH];
    int tid = threadIdx.x;
    for (int idx = tid; idx < GH * NE; idx += 256) {
        int k = idx >> 3, e = idx & 7;
        wt[e][k] = g2w[idx];
    }
    __syncthreads();
    int row  = (blockIdx.x * 256 + tid) >> 6;
    int lane = tid & 63;
    if (row >= B_) return;
    float a0 = G2[(size_t)row * GH + lane];
    float a1 = G2[(size_t)row * GH + 64 + lane];
    float p[NE];
    #pragma unroll
    for (int e = 0; e < NE; ++e)
        p[e] = a0 * wt[e][lane] + a1 * wt[e][lane + 64];
    #pragma unroll
    for (int o = 32; o; o >>= 1) {
        #pragma unroll
        for (int e = 0; e < NE; ++e) p[e] += __shfl_xor(p[e], o);
    }
    float mx = -1e30f;
    #pragma unroll
    for (int e = 0; e < NE; ++e) { p[e] += g2b[e]; mx = fmaxf(mx, p[e]); }
    float s = 0.0f;
    #pragma unroll
    for (int e = 0; e < NE; ++e) { p[e] = expf(p[e] - mx); s += p[e]; }
    float inv = 1.0f / s;
    if (lane == 0) {
        #pragma unroll
        for (int e = 0; e < NE; ++e) coeff[(size_t)row * NE + e] = p[e] * inv;
    }
}

// ---------- final mix: out[b,o] = sum_e cf[b,e] * P[b, e*16+o] ----------
__global__ __launch_bounds__(256) void k_mix(
    const float* __restrict__ P, const float* __restrict__ cf, float* __restrict__ out)
{
    int id = blockIdx.x * 256 + threadIdx.x;
    if (id >= B_ * ACTD) return;
    int b = id >> 4, o = id & 15;
    const float* pr = P + (size_t)b * 128 + o;
    const float* cr = cf + (size_t)b * 8;
    float s = 0.f;
    #pragma unroll
    for (int e = 0; e < 8; ++e) s += cr[e] * pr[e * 16];
    out[id] = s;
}

extern "C" void kernel_launch(void* const* d_in, const int* in_sizes, int n_in,
                              void* d_out, int out_size, void* d_ws, size_t ws_size,
                              hipStream_t stream)
{
    (void)in_sizes; (void)n_in; (void)out_size; (void)ws_size;
    const float* z   = (const float*)d_in[0];
    const float* c   = (const float*)d_in[1];
    const float* w0  = (const float*)d_in[2];
    const float* b0  = (const float*)d_in[3];
    const float* w1  = (const float*)d_in[4];
    const float* b1  = (const float*)d_in[5];
    const float* w2  = (const float*)d_in[6];
    const float* b2  = (const float*)d_in[7];
    const float* g0w = (const float*)d_in[8];
    const float* g0b = (const float*)d_in[9];
    const float* g1w = (const float*)d_in[10];
    const float* g1b = (const float*)d_in[11];
    const float* g2w = (const float*)d_in[12];
    const float* g2b = (const float*)d_in[13];
    const float* lng = (const float*)d_in[14];
    const float* lnb = (const float*)d_in[15];
    float* out = (float*)d_out;

    char* p = (char*)d_ws;
    auto alloc = [&](size_t n) { char* r = p; p += (n + 255) & ~(size_t)255; return r; };
    unsigned short* X0h = (unsigned short*)alloc((size_t)B_ * IN0 * 2);
    unsigned short* X0l = (unsigned short*)alloc((size_t)B_ * IN0 * 2);
    unsigned short* X1h = (unsigned short*)alloc((size_t)B_ * INTER * 2);
    unsigned short* X1l = (unsigned short*)alloc((size_t)B_ * INTER * 2);
    unsigned short* X2h = (unsigned short*)alloc((size_t)B_ * INTER * 2);
    unsigned short* X2l = (unsigned short*)alloc((size_t)B_ * INTER * 2);
    unsigned short* G1h = (unsigned short*)alloc((size_t)B_ * GH * 2);
    unsigned short* G1l = (unsigned short*)alloc((size_t)B_ * GH * 2);
    float* G2f = (float*)alloc((size_t)B_ * GH * 4);      // reused as P2 after gate_out
    float* cf  = (float*)alloc((size_t)B_ * NE * 4);
    unsigned short* T0h = (unsigned short*)alloc((size_t)NE * IN0 * HID * 2);
    unsigned short* T0l = (unsigned short*)alloc((size_t)NE * IN0 * HID * 2);
    unsigned short* T1h = (unsigned short*)alloc((size_t)NE * INTER * HID * 2);
    unsigned short* T1l = (unsigned short*)alloc((size_t)NE * INTER * HID * 2);
    unsigned short* T2h = (unsigned short*)alloc((size_t)NE * INTER * ACTD * 2);
    unsigned short* T2l = (unsigned short*)alloc((size_t)NE * INTER * ACTD * 2);
    unsigned short* G0Th = (unsigned short*)alloc((size_t)IN0 * GH * 2);
    unsigned short* G0Tl = (unsigned short*)alloc((size_t)IN0 * GH * 2);
    unsigned short* G1Th = (unsigned short*)alloc((size_t)GH * GH * 2);
    unsigned short* G1Tl = (unsigned short*)alloc((size_t)GH * GH * 2);
    float* P2 = G2f;

    k_prep_g<<<dim3(484), dim3(256), 0, stream>>>(w0, w1, w2, g0w, g1w,
        T0h, T0l, T1h, T1l, T2h, T2l, G0Th, G0Tl, G1Th, G1Tl);
    k_ln_concat2<<<dim3(B_ / 4), dim3(256), 0, stream>>>(z, c, lng, lnb,
        X0h, X0l, X1h, X1l, X2h, X2l);

    // gate MLP: X0 -> G1 (bf16 hi/lo) -> G2f (fp32+elu) -> coeff
    k_small64<5, 64, 1, 128, 0><<<dim3(256), dim3(256), 0, stream>>>(
        X0h, X0l, G0Th, G0Tl, g0b, nullptr, G1h, G1l);
    k_small64<4, 64, 2, 128, 0><<<dim3(256), dim3(256), 0, stream>>>(
        G1h, G1l, G1Th, G1Tl, g1b, G2f, nullptr, nullptr);
    k_gate_out<<<dim3(B_ / 4), dim3(256), 0, stream>>>(G2f, g2w, g2b, cf);

    // expert layers: e-sequential waves, A in VGPRs, tiny shared B tiles
    k_moe_seq<5><<<dim3(512), dim3(256), 0, stream>>>(
        X0h, X0l, T0h, T0l, b0, cf, X1h, X1l);
    k_moe_seq<9><<<dim3(512), dim3(256), 0, stream>>>(
        X1h, X1l, T1h, T1l, b1, cf, X2h, X2l);
    // final layer as plain GEMM over N = E*16 = 128, then coeff-mix
    k_small64<9, 32, 0, 128, 0><<<dim3(512), dim3(256), 0, stream>>>(
        X2h, X2l, T2h, T2l, b2, P2, nullptr, nullptr);
    k_mix<<<dim3(B_ * ACTD / 256), dim3(256), 0, stream>>>(P2, cf, out);
}